// Round 6
// baseline (240.738 us; speedup 1.0000x reference)
//
#include <hip/hip_runtime.h>
#include <hip/hip_bf16.h>

typedef __attribute__((ext_vector_type(8))) short bf16x8;
typedef __attribute__((ext_vector_type(4))) float f32x4;

static __device__ __forceinline__ float bflo(unsigned int w) {
    union { unsigned int i; float f; } u; u.i = w << 16; return u.f;
}
static __device__ __forceinline__ float bfhi(unsigned int w) {
    union { unsigned int i; float f; } u; u.i = w & 0xffff0000u; return u.f;
}
static __device__ __forceinline__ unsigned short f2bf(float f) {
    __hip_bfloat16 h = __float2bfloat16(f);
    union { __hip_bfloat16 b; unsigned short s; } u; u.b = h; return u.s;
}

// ---------------------------------------------------------------------------
// degree histogram over dst
// ---------------------------------------------------------------------------
__global__ void count_kernel(const int* __restrict__ dst, int* __restrict__ counts, int E) {
    int e = blockIdx.x * blockDim.x + threadIdx.x;
    if (e < E) atomicAdd(&counts[dst[e]], 1);
}

// ---------------------------------------------------------------------------
// single-block scan, coalesced column-major bucket order.
// Consumers use row_ptr[v] + counts[v] as bucket end (order-free).
// ---------------------------------------------------------------------------
__global__ __launch_bounds__(256) void scan_kernel(const int* __restrict__ counts,
                                                   int* __restrict__ row_ptr,
                                                   float* __restrict__ dinv, int n) {
    int t = threadIdx.x;
    int rows = n >> 8;                 // 64
    int s = 0;
    for (int i = 0; i < rows; ++i) s += counts[i * 256 + t];   // coalesced
    __shared__ int sums[256];
    sums[t] = s;
    __syncthreads();
#pragma unroll
    for (int off = 1; off < 256; off <<= 1) {
        int v = (t >= off) ? sums[t - off] : 0;
        __syncthreads();
        sums[t] += v;
        __syncthreads();
    }
    int run = (t > 0) ? sums[t - 1] : 0;
    for (int i = 0; i < rows; ++i) {
        int v = i * 256 + t;
        int c = counts[v];
        row_ptr[v] = run;              // coalesced
        dinv[v] = rsqrtf((float)(c + 1));
        run += c;
    }
}

// ---------------------------------------------------------------------------
// scatter edges into CSR buckets as packed {src, dinv[src]} records
// ---------------------------------------------------------------------------
__global__ void scatter_kernel(const int* __restrict__ src, const int* __restrict__ dst,
                               const int* __restrict__ row_ptr, int* __restrict__ wp,
                               const float* __restrict__ dinv,
                               int2* __restrict__ edges, int E) {
    int e = blockIdx.x * blockDim.x + threadIdx.x;
    if (e < E) {
        int d = dst[e];
        int s = src[e];
        int p = atomicAdd(&wp[d], 1);
        int2 pk;
        pk.x = s;
        pk.y = __float_as_int(dinv[s]);
        edges[row_ptr[d] + p] = pk;
    }
}

// ---------------------------------------------------------------------------
// merged prep: h0 (bf16) + transposed bf16 weights + zero counts/wp.
// threads [0, H)              : h0 rows (8 dims per thread), H = n*16
// threads [H, H+73728)        : W1t (32768) | W2t (32768) | Wlt (8192)
// threads [H+73728, +2n)      : zero counts, wp
// ---------------------------------------------------------------------------
__global__ void prep_kernel(const int* __restrict__ x, const float* __restrict__ emb,
                            const float* __restrict__ W1, const float* __restrict__ W2,
                            const float* __restrict__ Wl,
                            unsigned short* __restrict__ h0,
                            unsigned short* __restrict__ W1t,
                            unsigned short* __restrict__ W2t,
                            unsigned short* __restrict__ Wlt,
                            int* __restrict__ counts, int* __restrict__ wp,
                            int nu, int n) {
    int i = blockIdx.x * blockDim.x + threadIdx.x;
    int H = n * 16;
    if (i < H) {
        int node = i >> 4, c8 = i & 15;
        int row = (node < nu) ? 0 : (x[node] - nu + 1);
        float4 f0 = reinterpret_cast<const float4*>(emb)[(size_t)row * 32 + c8 * 2];
        float4 f1 = reinterpret_cast<const float4*>(emb)[(size_t)row * 32 + c8 * 2 + 1];
        union { unsigned short s[8]; uint4 v; } o;
        o.s[0] = f2bf(f0.x); o.s[1] = f2bf(f0.y); o.s[2] = f2bf(f0.z); o.s[3] = f2bf(f0.w);
        o.s[4] = f2bf(f1.x); o.s[5] = f2bf(f1.y); o.s[6] = f2bf(f1.z); o.s[7] = f2bf(f1.w);
        *reinterpret_cast<uint4*>(h0 + (size_t)node * 128 + c8 * 8) = o.v;
        return;
    }
    int j = i - H;
    if (j < 32768) {                       // W1t[nn][kk] = W1[kk][nn], 256x128
        int nn = j >> 7, kk = j & 127;
        W1t[j] = f2bf(W1[kk * 256 + nn]);
        return;
    }
    if (j < 65536) {                       // W2t[nn][kk] = W2[kk][nn], 128x256
        int jj = j - 32768;
        int nn = jj >> 8, kk = jj & 255;
        W2t[jj] = f2bf(W2[kk * 128 + nn]);
        return;
    }
    if (j < 73728) {                       // Wlt[nn][kk] = Wl[kk][nn], 64x128
        int jj = j - 65536;
        int nn = jj >> 7, kk = jj & 127;
        Wlt[jj] = f2bf(Wl[kk * 64 + nn]);
        return;
    }
    int z = j - 73728;
    if (z < n) { counts[z] = 0; return; }
    z -= n;
    if (z < n) { wp[z] = 0; }
}

// ---------------------------------------------------------------------------
// aggregation (bf16 in/out, fp32 accumulate), ONE WAVE per node.
// lane&15 -> 8-dim segment; lane>>4 -> edge subgroup (4); shfl-xor reduce.
// Packed edges: one 8B load gives {src, weight}. 2x unroll.
// ---------------------------------------------------------------------------
__global__ __launch_bounds__(64) void agg_bf16_kernel(
    const unsigned short* __restrict__ in, unsigned short* __restrict__ out,
    const int* __restrict__ row_ptr, const int* __restrict__ cnt,
    const int2* __restrict__ edges, const float* __restrict__ dinv,
    const float* __restrict__ bias, int relu) {
    int v = blockIdx.x;
    int lane = threadIdx.x;
    int l16 = lane & 15;
    int g = lane >> 4;
    float acc[8] = {0.f, 0.f, 0.f, 0.f, 0.f, 0.f, 0.f, 0.f};
    int s0 = row_ptr[v];
    int s1 = s0 + cnt[v];
    int e = s0 + g;
    for (; e + 4 < s1; e += 8) {
        int2 pa = edges[e];
        int2 pb = edges[e + 4];
        float wa = __int_as_float(pa.y);
        float wb = __int_as_float(pb.y);
        uint4 ra = *reinterpret_cast<const uint4*>(in + (size_t)pa.x * 128 + l16 * 8);
        uint4 rb = *reinterpret_cast<const uint4*>(in + (size_t)pb.x * 128 + l16 * 8);
        acc[0] = fmaf(wa, bflo(ra.x), acc[0]);
        acc[1] = fmaf(wa, bfhi(ra.x), acc[1]);
        acc[2] = fmaf(wa, bflo(ra.y), acc[2]);
        acc[3] = fmaf(wa, bfhi(ra.y), acc[3]);
        acc[4] = fmaf(wa, bflo(ra.z), acc[4]);
        acc[5] = fmaf(wa, bfhi(ra.z), acc[5]);
        acc[6] = fmaf(wa, bflo(ra.w), acc[6]);
        acc[7] = fmaf(wa, bfhi(ra.w), acc[7]);
        acc[0] = fmaf(wb, bflo(rb.x), acc[0]);
        acc[1] = fmaf(wb, bfhi(rb.x), acc[1]);
        acc[2] = fmaf(wb, bflo(rb.y), acc[2]);
        acc[3] = fmaf(wb, bfhi(rb.y), acc[3]);
        acc[4] = fmaf(wb, bflo(rb.z), acc[4]);
        acc[5] = fmaf(wb, bfhi(rb.z), acc[5]);
        acc[6] = fmaf(wb, bflo(rb.w), acc[6]);
        acc[7] = fmaf(wb, bfhi(rb.w), acc[7]);
    }
    if (e < s1) {
        int2 pa = edges[e];
        float wa = __int_as_float(pa.y);
        uint4 ra = *reinterpret_cast<const uint4*>(in + (size_t)pa.x * 128 + l16 * 8);
        acc[0] = fmaf(wa, bflo(ra.x), acc[0]);
        acc[1] = fmaf(wa, bfhi(ra.x), acc[1]);
        acc[2] = fmaf(wa, bflo(ra.y), acc[2]);
        acc[3] = fmaf(wa, bfhi(ra.y), acc[3]);
        acc[4] = fmaf(wa, bflo(ra.z), acc[4]);
        acc[5] = fmaf(wa, bfhi(ra.z), acc[5]);
        acc[6] = fmaf(wa, bflo(ra.w), acc[6]);
        acc[7] = fmaf(wa, bfhi(ra.w), acc[7]);
    }
#pragma unroll
    for (int d = 0; d < 8; ++d) {
        acc[d] += __shfl_xor(acc[d], 16, 64);
        acc[d] += __shfl_xor(acc[d], 32, 64);
    }
    if (g == 0) {
        float dv = dinv[v];
        uint4 sp = *reinterpret_cast<const uint4*>(in + (size_t)v * 128 + l16 * 8);
        float self[8] = {bflo(sp.x), bfhi(sp.x), bflo(sp.y), bfhi(sp.y),
                         bflo(sp.z), bfhi(sp.z), bflo(sp.w), bfhi(sp.w)};
        union { unsigned short s[8]; uint4 u; } o;
#pragma unroll
        for (int d = 0; d < 8; ++d) {
            float val = (acc[d] + dv * self[d]) * dv;
            if (bias) val += bias[l16 * 8 + d];
            if (relu) val = fmaxf(val, 0.f);
            o.s[d] = f2bf(val);
        }
        *reinterpret_cast<uint4*>(out + (size_t)v * 128 + l16 * 8) = o.u;
    }
}

// ---------------------------------------------------------------------------
// MFMA GEMM: C(MxN, bf16) = act(A(MxK, bf16) @ Bt(NxK, bf16)^T + bias)
// grid (M/64, N/64), 256 thr = 4 waves; wave w handles rows [bm+16w, +16).
// ---------------------------------------------------------------------------
__global__ __launch_bounds__(256) void mfma_gemm_kernel(
    const unsigned short* __restrict__ A, const unsigned short* __restrict__ Bt,
    const float* __restrict__ bias, unsigned short* __restrict__ C,
    int M, int N, int K, int relu) {
    int w = threadIdx.x >> 6, lane = threadIdx.x & 63;
    int r0 = blockIdx.x * 64 + w * 16;
    int bn = blockIdx.y * 64;
    int lr = lane & 15, kg = (lane >> 4) * 8;
    f32x4 acc[4] = {{0,0,0,0},{0,0,0,0},{0,0,0,0},{0,0,0,0}};
    for (int k0 = 0; k0 < K; k0 += 32) {
        bf16x8 a = *reinterpret_cast<const bf16x8*>(A + (size_t)(r0 + lr) * K + k0 + kg);
#pragma unroll
        for (int c = 0; c < 4; ++c) {
            bf16x8 b = *reinterpret_cast<const bf16x8*>(Bt + (size_t)(bn + c * 16 + lr) * K + k0 + kg);
            acc[c] = __builtin_amdgcn_mfma_f32_16x16x32_bf16(a, b, acc[c], 0, 0, 0);
        }
    }
    int rq = (lane >> 4) * 4;
#pragma unroll
    for (int c = 0; c < 4; ++c) {
        int col = bn + c * 16 + lr;
        float bs = bias ? bias[col] : 0.f;
#pragma unroll
        for (int q = 0; q < 4; ++q) {
            float vv = acc[c][q] + bs;
            if (relu) vv = fmaxf(vv, 0.f);
            C[(size_t)(r0 + rq + q) * N + col] = f2bf(vv);
        }
    }
}

// ---------------------------------------------------------------------------
// final: out[i][j] = clip(dot64(users[i], items[j]), 1, 5)  via bf16 MFMA.
// Block = 4 waves; each wave does a 64x64 tile -> block tile 128x128.
// Non-temporal stores: 256 MB streaming output, no reuse.
// ---------------------------------------------------------------------------
__global__ __launch_bounds__(256) void final_gemm_kernel(
    const short* __restrict__ h3b, float* __restrict__ out, int nu, int ni) {
    int wid = threadIdx.x >> 6, lane = threadIdx.x & 63;
    int row0 = blockIdx.x * 128 + (wid >> 1) * 64;
    int col0 = blockIdx.y * 128 + (wid & 1) * 64;
    int lr = lane & 15;
    int kg = (lane >> 4) * 8;
    const short* Au = h3b;                       // users
    const short* Bi = h3b + (size_t)nu * 64;     // items
    bf16x8 a[4][2], b[4][2];
#pragma unroll
    for (int r = 0; r < 4; ++r)
#pragma unroll
        for (int kt = 0; kt < 2; ++kt) {
            a[r][kt] = *reinterpret_cast<const bf16x8*>(Au + (size_t)(row0 + r * 16 + lr) * 64 + kt * 32 + kg);
            b[r][kt] = *reinterpret_cast<const bf16x8*>(Bi + (size_t)(col0 + r * 16 + lr) * 64 + kt * 32 + kg);
        }
    f32x4 acc[4][4];
#pragma unroll
    for (int r = 0; r < 4; ++r)
#pragma unroll
        for (int c = 0; c < 4; ++c) {
            f32x4 z = {0.f, 0.f, 0.f, 0.f};
            z = __builtin_amdgcn_mfma_f32_16x16x32_bf16(a[r][0], b[c][0], z, 0, 0, 0);
            z = __builtin_amdgcn_mfma_f32_16x16x32_bf16(a[r][1], b[c][1], z, 0, 0, 0);
            acc[r][c] = z;
        }
    int rq = (lane >> 4) * 4;
#pragma unroll
    for (int r = 0; r < 4; ++r)
#pragma unroll
        for (int c = 0; c < 4; ++c)
#pragma unroll
            for (int q = 0; q < 4; ++q) {
                float v = acc[r][c][q];
                v = fminf(fmaxf(v, 1.f), 5.f);
                __builtin_nontemporal_store(
                    v, &out[(size_t)(row0 + r * 16 + rq + q) * ni + col0 + c * 16 + lr]);
            }
}

// ---------------------------------------------------------------------------
extern "C" void kernel_launch(void* const* d_in, const int* in_sizes, int n_in,
                              void* d_out, int out_size, void* d_ws, size_t ws_size,
                              hipStream_t stream) {
    const int*   x   = (const int*)d_in[0];
    const int*   ei  = (const int*)d_in[1];
    const float* emb = (const float*)d_in[3];
    const float* W1  = (const float*)d_in[4];
    const float* b1  = (const float*)d_in[5];
    const float* W2  = (const float*)d_in[6];
    const float* b2  = (const float*)d_in[7];
    const float* Wl  = (const float*)d_in[8];
    const float* bl  = (const float*)d_in[9];
    float* out = (float*)d_out;

    const int n   = in_sizes[0];                 // 16384
    const int E   = in_sizes[1] / 2;             // 524288
    const int h1d = in_sizes[5];                 // 256
    const int d   = in_sizes[4] / h1d;           // 128
    const int embrows = in_sizes[3] / d;         // 8193
    const int nu  = n - (embrows - 1);           // 8192
    const int ni  = n - nu;                      // 8192

    const int* srcp = ei;
    const int* dstp = ei + E;

    char* w = (char*)d_ws;
    int*   counts  = (int*)(w + 0);                         // 64 KB
    int*   row_ptr = (int*)(w + (64 << 10));                // 64 KB
    int*   wp      = (int*)(w + (128 << 10));               // 64 KB
    float* dinv    = (float*)(w + (192 << 10));             // 64 KB
    unsigned short* W1t = (unsigned short*)(w + (256 << 10));  // 64 KB
    unsigned short* W2t = (unsigned short*)(w + (320 << 10));  // 64 KB
    unsigned short* Wlt = (unsigned short*)(w + (384 << 10));  // 16 KB
    int2*  edges   = (int2*)(w + (1 << 20));                // 4 MB
    unsigned short* h0b  = (unsigned short*)(w + (8  << 20));  // 4 MB
    unsigned short* z1b  = (unsigned short*)(w + (12 << 20));  // 4 MB
    unsigned short* h1b  = (unsigned short*)(w + (16 << 20));  // 8 MB
    unsigned short* hw2b = (unsigned short*)(w + (24 << 20));  // 4 MB
    unsigned short* h2b  = (unsigned short*)(w + (28 << 20));  // 4 MB
    unsigned short* h3b  = (unsigned short*)(w + (32 << 20));  // 2 MB

    // prep: h0 bf16 + transposed bf16 weights + zero counters (one dispatch)
    {
        int total = n * 16 + 73728 + 2 * n;
        prep_kernel<<<(total + 255) / 256, 256, 0, stream>>>(
            x, emb, W1, W2, Wl, h0b, W1t, W2t, Wlt, counts, wp, nu, n);
    }

    // graph structure
    count_kernel<<<(E + 255) / 256, 256, 0, stream>>>(dstp, counts, E);
    scan_kernel<<<1, 256, 0, stream>>>(counts, row_ptr, dinv, n);
    scatter_kernel<<<(E + 255) / 256, 256, 0, stream>>>(srcp, dstp, row_ptr, wp, dinv, edges, E);

    // conv1: z1 = A·h0 ; h1 = relu(z1 @ W1 + b1)
    agg_bf16_kernel<<<n, 64, 0, stream>>>(h0b, z1b, row_ptr, counts, edges, dinv, nullptr, 0);
    {
        dim3 g(n / 64, h1d / 64);
        mfma_gemm_kernel<<<g, 256, 0, stream>>>(z1b, W1t, b1, h1b, n, h1d, d, 1);
    }

    // conv2: hw2 = h1 @ W2 ; h2 = relu(A·hw2 + b2)
    {
        dim3 g(n / 64, 128 / 64);
        mfma_gemm_kernel<<<g, 256, 0, stream>>>(h1b, W2t, nullptr, hw2b, n, 128, h1d, 0);
    }
    agg_bf16_kernel<<<n, 64, 0, stream>>>(hw2b, h2b, row_ptr, counts, edges, dinv, b2, 1);

    // h3 = relu(h2 @ Wl + bl)
    {
        dim3 g(n / 64, 64 / 64);
        mfma_gemm_kernel<<<g, 256, 0, stream>>>(h2b, Wlt, bl, h3b, n, 64, 128, 1);
    }

    // result = clip(users @ items.T, 1, 5)
    {
        dim3 g(nu / 128, ni / 128);
        final_gemm_kernel<<<g, 256, 0, stream>>>((const short*)h3b, out, nu, ni);
    }
}

// Round 7
// 195.481 us; speedup vs baseline: 1.2315x; 1.2315x over previous
//
#include <hip/hip_runtime.h>
#include <hip/hip_bf16.h>

typedef __attribute__((ext_vector_type(8))) short bf16x8;
typedef __attribute__((ext_vector_type(4))) float f32x4;

static __device__ __forceinline__ float bflo(unsigned int w) {
    union { unsigned int i; float f; } u; u.i = w << 16; return u.f;
}
static __device__ __forceinline__ float bfhi(unsigned int w) {
    union { unsigned int i; float f; } u; u.i = w & 0xffff0000u; return u.f;
}
static __device__ __forceinline__ unsigned short f2bf(float f) {
    __hip_bfloat16 h = __float2bfloat16(f);
    union { __hip_bfloat16 b; unsigned short s; } u; u.b = h; return u.s;
}

// ---------------------------------------------------------------------------
// degree histogram over dst
// ---------------------------------------------------------------------------
__global__ void count_kernel(const int* __restrict__ dst, int* __restrict__ counts, int E) {
    int e = blockIdx.x * blockDim.x + threadIdx.x;
    if (e < E) atomicAdd(&counts[dst[e]], 1);
}

// ---------------------------------------------------------------------------
// single-block scan, coalesced column-major bucket order.
// Consumers use row_ptr[v] + counts[v] as bucket end (order-free).
// ---------------------------------------------------------------------------
__global__ __launch_bounds__(256) void scan_kernel(const int* __restrict__ counts,
                                                   int* __restrict__ row_ptr,
                                                   float* __restrict__ dinv, int n) {
    int t = threadIdx.x;
    int rows = n >> 8;                 // 64
    int s = 0;
    for (int i = 0; i < rows; ++i) s += counts[i * 256 + t];   // coalesced
    __shared__ int sums[256];
    sums[t] = s;
    __syncthreads();
#pragma unroll
    for (int off = 1; off < 256; off <<= 1) {
        int v = (t >= off) ? sums[t - off] : 0;
        __syncthreads();
        sums[t] += v;
        __syncthreads();
    }
    int run = (t > 0) ? sums[t - 1] : 0;
    for (int i = 0; i < rows; ++i) {
        int v = i * 256 + t;
        int c = counts[v];
        row_ptr[v] = run;              // coalesced
        dinv[v] = rsqrtf((float)(c + 1));
        run += c;
    }
}

// ---------------------------------------------------------------------------
// scatter edges into CSR buckets as packed {src, dinv[src]} records
// ---------------------------------------------------------------------------
__global__ void scatter_kernel(const int* __restrict__ src, const int* __restrict__ dst,
                               const int* __restrict__ row_ptr, int* __restrict__ wp,
                               const float* __restrict__ dinv,
                               int2* __restrict__ edges, int E) {
    int e = blockIdx.x * blockDim.x + threadIdx.x;
    if (e < E) {
        int d = dst[e];
        int s = src[e];
        int p = atomicAdd(&wp[d], 1);
        int2 pk;
        pk.x = s;
        pk.y = __float_as_int(dinv[s]);
        edges[row_ptr[d] + p] = pk;
    }
}

// ---------------------------------------------------------------------------
// merged prep: h0 (bf16) + transposed bf16 weights + zero counts/wp.
// ---------------------------------------------------------------------------
__global__ void prep_kernel(const int* __restrict__ x, const float* __restrict__ emb,
                            const float* __restrict__ W1, const float* __restrict__ W2,
                            const float* __restrict__ Wl,
                            unsigned short* __restrict__ h0,
                            unsigned short* __restrict__ W1t,
                            unsigned short* __restrict__ W2t,
                            unsigned short* __restrict__ Wlt,
                            int* __restrict__ counts, int* __restrict__ wp,
                            int nu, int n) {
    int i = blockIdx.x * blockDim.x + threadIdx.x;
    int H = n * 16;
    if (i < H) {
        int node = i >> 4, c8 = i & 15;
        int row = (node < nu) ? 0 : (x[node] - nu + 1);
        float4 f0 = reinterpret_cast<const float4*>(emb)[(size_t)row * 32 + c8 * 2];
        float4 f1 = reinterpret_cast<const float4*>(emb)[(size_t)row * 32 + c8 * 2 + 1];
        union { unsigned short s[8]; uint4 v; } o;
        o.s[0] = f2bf(f0.x); o.s[1] = f2bf(f0.y); o.s[2] = f2bf(f0.z); o.s[3] = f2bf(f0.w);
        o.s[4] = f2bf(f1.x); o.s[5] = f2bf(f1.y); o.s[6] = f2bf(f1.z); o.s[7] = f2bf(f1.w);
        *reinterpret_cast<uint4*>(h0 + (size_t)node * 128 + c8 * 8) = o.v;
        return;
    }
    int j = i - H;
    if (j < 32768) {                       // W1t[nn][kk] = W1[kk][nn], 256x128
        int nn = j >> 7, kk = j & 127;
        W1t[j] = f2bf(W1[kk * 256 + nn]);
        return;
    }
    if (j < 65536) {                       // W2t[nn][kk] = W2[kk][nn], 128x256
        int jj = j - 32768;
        int nn = jj >> 8, kk = jj & 255;
        W2t[jj] = f2bf(W2[kk * 128 + nn]);
        return;
    }
    if (j < 73728) {                       // Wlt[nn][kk] = Wl[kk][nn], 64x128
        int jj = j - 65536;
        int nn = jj >> 7, kk = jj & 127;
        Wlt[jj] = f2bf(Wl[kk * 64 + nn]);
        return;
    }
    int z = j - 73728;
    if (z < n) { counts[z] = 0; return; }
    z -= n;
    if (z < n) { wp[z] = 0; }
}

// ---------------------------------------------------------------------------
// aggregation (bf16 in/out, fp32 accumulate), ONE WAVE per node.
// Packed edges: one 8B load gives {src, weight}. 2x unroll.
// ---------------------------------------------------------------------------
__global__ __launch_bounds__(64) void agg_bf16_kernel(
    const unsigned short* __restrict__ in, unsigned short* __restrict__ out,
    const int* __restrict__ row_ptr, const int* __restrict__ cnt,
    const int2* __restrict__ edges, const float* __restrict__ dinv,
    const float* __restrict__ bias, int relu) {
    int v = blockIdx.x;
    int lane = threadIdx.x;
    int l16 = lane & 15;
    int g = lane >> 4;
    float acc[8] = {0.f, 0.f, 0.f, 0.f, 0.f, 0.f, 0.f, 0.f};
    int s0 = row_ptr[v];
    int s1 = s0 + cnt[v];
    int e = s0 + g;
    for (; e + 4 < s1; e += 8) {
        int2 pa = edges[e];
        int2 pb = edges[e + 4];
        float wa = __int_as_float(pa.y);
        float wb = __int_as_float(pb.y);
        uint4 ra = *reinterpret_cast<const uint4*>(in + (size_t)pa.x * 128 + l16 * 8);
        uint4 rb = *reinterpret_cast<const uint4*>(in + (size_t)pb.x * 128 + l16 * 8);
        acc[0] = fmaf(wa, bflo(ra.x), acc[0]);
        acc[1] = fmaf(wa, bfhi(ra.x), acc[1]);
        acc[2] = fmaf(wa, bflo(ra.y), acc[2]);
        acc[3] = fmaf(wa, bfhi(ra.y), acc[3]);
        acc[4] = fmaf(wa, bflo(ra.z), acc[4]);
        acc[5] = fmaf(wa, bfhi(ra.z), acc[5]);
        acc[6] = fmaf(wa, bflo(ra.w), acc[6]);
        acc[7] = fmaf(wa, bfhi(ra.w), acc[7]);
        acc[0] = fmaf(wb, bflo(rb.x), acc[0]);
        acc[1] = fmaf(wb, bfhi(rb.x), acc[1]);
        acc[2] = fmaf(wb, bflo(rb.y), acc[2]);
        acc[3] = fmaf(wb, bfhi(rb.y), acc[3]);
        acc[4] = fmaf(wb, bflo(rb.z), acc[4]);
        acc[5] = fmaf(wb, bfhi(rb.z), acc[5]);
        acc[6] = fmaf(wb, bflo(rb.w), acc[6]);
        acc[7] = fmaf(wb, bfhi(rb.w), acc[7]);
    }
    if (e < s1) {
        int2 pa = edges[e];
        float wa = __int_as_float(pa.y);
        uint4 ra = *reinterpret_cast<const uint4*>(in + (size_t)pa.x * 128 + l16 * 8);
        acc[0] = fmaf(wa, bflo(ra.x), acc[0]);
        acc[1] = fmaf(wa, bfhi(ra.x), acc[1]);
        acc[2] = fmaf(wa, bflo(ra.y), acc[2]);
        acc[3] = fmaf(wa, bfhi(ra.y), acc[3]);
        acc[4] = fmaf(wa, bflo(ra.z), acc[4]);
        acc[5] = fmaf(wa, bfhi(ra.z), acc[5]);
        acc[6] = fmaf(wa, bflo(ra.w), acc[6]);
        acc[7] = fmaf(wa, bfhi(ra.w), acc[7]);
    }
#pragma unroll
    for (int d = 0; d < 8; ++d) {
        acc[d] += __shfl_xor(acc[d], 16, 64);
        acc[d] += __shfl_xor(acc[d], 32, 64);
    }
    if (g == 0) {
        float dv = dinv[v];
        uint4 sp = *reinterpret_cast<const uint4*>(in + (size_t)v * 128 + l16 * 8);
        float self[8] = {bflo(sp.x), bfhi(sp.x), bflo(sp.y), bfhi(sp.y),
                         bflo(sp.z), bfhi(sp.z), bflo(sp.w), bfhi(sp.w)};
        union { unsigned short s[8]; uint4 u; } o;
#pragma unroll
        for (int d = 0; d < 8; ++d) {
            float val = (acc[d] + dv * self[d]) * dv;
            if (bias) val += bias[l16 * 8 + d];
            if (relu) val = fmaxf(val, 0.f);
            o.s[d] = f2bf(val);
        }
        *reinterpret_cast<uint4*>(out + (size_t)v * 128 + l16 * 8) = o.u;
    }
}

// ---------------------------------------------------------------------------
// MFMA GEMM: C(MxN, bf16) = act(A(MxK, bf16) @ Bt(NxK, bf16)^T + bias)
// ---------------------------------------------------------------------------
__global__ __launch_bounds__(256) void mfma_gemm_kernel(
    const unsigned short* __restrict__ A, const unsigned short* __restrict__ Bt,
    const float* __restrict__ bias, unsigned short* __restrict__ C,
    int M, int N, int K, int relu) {
    int w = threadIdx.x >> 6, lane = threadIdx.x & 63;
    int r0 = blockIdx.x * 64 + w * 16;
    int bn = blockIdx.y * 64;
    int lr = lane & 15, kg = (lane >> 4) * 8;
    f32x4 acc[4] = {{0,0,0,0},{0,0,0,0},{0,0,0,0},{0,0,0,0}};
    for (int k0 = 0; k0 < K; k0 += 32) {
        bf16x8 a = *reinterpret_cast<const bf16x8*>(A + (size_t)(r0 + lr) * K + k0 + kg);
#pragma unroll
        for (int c = 0; c < 4; ++c) {
            bf16x8 b = *reinterpret_cast<const bf16x8*>(Bt + (size_t)(bn + c * 16 + lr) * K + k0 + kg);
            acc[c] = __builtin_amdgcn_mfma_f32_16x16x32_bf16(a, b, acc[c], 0, 0, 0);
        }
    }
    int rq = (lane >> 4) * 4;
#pragma unroll
    for (int c = 0; c < 4; ++c) {
        int col = bn + c * 16 + lr;
        float bs = bias ? bias[col] : 0.f;
#pragma unroll
        for (int q = 0; q < 4; ++q) {
            float vv = acc[c][q] + bs;
            if (relu) vv = fmaxf(vv, 0.f);
            C[(size_t)(r0 + rq + q) * N + col] = f2bf(vv);
        }
    }
}

// ---------------------------------------------------------------------------
// final: out[i][j] = clip(dot64(users[i], items[j]), 1, 5)  via bf16 MFMA.
// Block = 4 waves; each wave a 64x64 tile -> block tile 128x128.
// Epilogue: per-wave LDS transpose chunk -> float4 stores (256B/instr segments).
// ---------------------------------------------------------------------------
__global__ __launch_bounds__(256) void final_gemm_kernel(
    const short* __restrict__ h3b, float* __restrict__ out, int nu, int ni) {
    __shared__ float tile[4][16][65];   // per-wave chunk, pad 65 (16.6 KB)
    int wid = threadIdx.x >> 6, lane = threadIdx.x & 63;
    int row0 = blockIdx.x * 128 + (wid >> 1) * 64;
    int col0 = blockIdx.y * 128 + (wid & 1) * 64;
    int lr = lane & 15;
    int kg = (lane >> 4) * 8;
    const short* Au = h3b;                       // users
    const short* Bi = h3b + (size_t)nu * 64;     // items
    bf16x8 a[4][2], b[4][2];
#pragma unroll
    for (int r = 0; r < 4; ++r)
#pragma unroll
        for (int kt = 0; kt < 2; ++kt) {
            a[r][kt] = *reinterpret_cast<const bf16x8*>(Au + (size_t)(row0 + r * 16 + lr) * 64 + kt * 32 + kg);
            b[r][kt] = *reinterpret_cast<const bf16x8*>(Bi + (size_t)(col0 + r * 16 + lr) * 64 + kt * 32 + kg);
        }
    f32x4 acc[4][4];
#pragma unroll
    for (int r = 0; r < 4; ++r)
#pragma unroll
        for (int c = 0; c < 4; ++c) {
            f32x4 z = {0.f, 0.f, 0.f, 0.f};
            z = __builtin_amdgcn_mfma_f32_16x16x32_bf16(a[r][0], b[c][0], z, 0, 0, 0);
            z = __builtin_amdgcn_mfma_f32_16x16x32_bf16(a[r][1], b[c][1], z, 0, 0, 0);
            acc[r][c] = z;
        }
    int rq = (lane >> 4) * 4;     // C-layout row group within 16
    int orow = lane >> 4;         // output sub-row 0..3
#pragma unroll
    for (int r = 0; r < 4; ++r) {
        __syncthreads();
        // scatter chunk r (16 rows x 64 cols) into LDS
#pragma unroll
        for (int c = 0; c < 4; ++c)
#pragma unroll
            for (int q = 0; q < 4; ++q) {
                float v = acc[r][c][q];
                v = fminf(fmaxf(v, 1.f), 5.f);
                tile[wid][rq + q][c * 16 + lr] = v;
            }
        __syncthreads();
        // read back as rows -> 16B/lane stores, 16 lanes = 256B contiguous
#pragma unroll
        for (int rr = 0; rr < 4; ++rr) {
            float4 vv = *reinterpret_cast<const float4*>(&tile[wid][rr * 4 + orow][lr * 4]);
            *reinterpret_cast<float4*>(
                &out[(size_t)(row0 + r * 16 + rr * 4 + orow) * ni + col0 + lr * 4]) = vv;
        }
    }
}

// ---------------------------------------------------------------------------
extern "C" void kernel_launch(void* const* d_in, const int* in_sizes, int n_in,
                              void* d_out, int out_size, void* d_ws, size_t ws_size,
                              hipStream_t stream) {
    const int*   x   = (const int*)d_in[0];
    const int*   ei  = (const int*)d_in[1];
    const float* emb = (const float*)d_in[3];
    const float* W1  = (const float*)d_in[4];
    const float* b1  = (const float*)d_in[5];
    const float* W2  = (const float*)d_in[6];
    const float* b2  = (const float*)d_in[7];
    const float* Wl  = (const float*)d_in[8];
    const float* bl  = (const float*)d_in[9];
    float* out = (float*)d_out;

    const int n   = in_sizes[0];                 // 16384
    const int E   = in_sizes[1] / 2;             // 524288
    const int h1d = in_sizes[5];                 // 256
    const int d   = in_sizes[4] / h1d;           // 128
    const int embrows = in_sizes[3] / d;         // 8193
    const int nu  = n - (embrows - 1);           // 8192
    const int ni  = n - nu;                      // 8192

    const int* srcp = ei;
    const int* dstp = ei + E;

    char* w = (char*)d_ws;
    int*   counts  = (int*)(w + 0);                         // 64 KB
    int*   row_ptr = (int*)(w + (64 << 10));                // 64 KB
    int*   wp      = (int*)(w + (128 << 10));               // 64 KB
    float* dinv    = (float*)(w + (192 << 10));             // 64 KB
    unsigned short* W1t = (unsigned short*)(w + (256 << 10));  // 64 KB
    unsigned short* W2t = (unsigned short*)(w + (320 << 10));  // 64 KB
    unsigned short* Wlt = (unsigned short*)(w + (384 << 10));  // 16 KB
    int2*  edges   = (int2*)(w + (1 << 20));                // 4 MB
    unsigned short* h0b  = (unsigned short*)(w + (8  << 20));  // 4 MB
    unsigned short* z1b  = (unsigned short*)(w + (12 << 20));  // 4 MB
    unsigned short* h1b  = (unsigned short*)(w + (16 << 20));  // 8 MB
    unsigned short* hw2b = (unsigned short*)(w + (24 << 20));  // 4 MB
    unsigned short* h2b  = (unsigned short*)(w + (28 << 20));  // 4 MB
    unsigned short* h3b  = (unsigned short*)(w + (32 << 20));  // 2 MB

    // prep: h0 bf16 + transposed bf16 weights + zero counters (one dispatch)
    {
        int total = n * 16 + 73728 + 2 * n;
        prep_kernel<<<(total + 255) / 256, 256, 0, stream>>>(
            x, emb, W1, W2, Wl, h0b, W1t, W2t, Wlt, counts, wp, nu, n);
    }

    // graph structure
    count_kernel<<<(E + 255) / 256, 256, 0, stream>>>(dstp, counts, E);
    scan_kernel<<<1, 256, 0, stream>>>(counts, row_ptr, dinv, n);
    scatter_kernel<<<(E + 255) / 256, 256, 0, stream>>>(srcp, dstp, row_ptr, wp, dinv, edges, E);

    // conv1: z1 = A·h0 ; h1 = relu(z1 @ W1 + b1)
    agg_bf16_kernel<<<n, 64, 0, stream>>>(h0b, z1b, row_ptr, counts, edges, dinv, nullptr, 0);
    {
        dim3 g(n / 64, h1d / 64);
        mfma_gemm_kernel<<<g, 256, 0, stream>>>(z1b, W1t, b1, h1b, n, h1d, d, 1);
    }

    // conv2: hw2 = h1 @ W2 ; h2 = relu(A·hw2 + b2)
    {
        dim3 g(n / 64, 128 / 64);
        mfma_gemm_kernel<<<g, 256, 0, stream>>>(h1b, W2t, nullptr, hw2b, n, 128, h1d, 0);
    }
    agg_bf16_kernel<<<n, 64, 0, stream>>>(hw2b, h2b, row_ptr, counts, edges, dinv, b2, 1);

    // h3 = relu(h2 @ Wl + bl)
    {
        dim3 g(n / 64, 64 / 64);
        mfma_gemm_kernel<<<g, 256, 0, stream>>>(h2b, Wlt, bl, h3b, n, 64, 128, 1);
    }

    // result = clip(users @ items.T, 1, 5)
    {
        dim3 g(nu / 128, ni / 128);
        final_gemm_kernel<<<g, 256, 0, stream>>>((const short*)h3b, out, nu, ni);
    }
}